// Round 8
// baseline (336.810 us; speedup 1.0000x reference)
//
#include <hip/hip_runtime.h>
#include <math.h>

#define BNEPS 1e-3f
#define LOG2E 1.44269504f

typedef __attribute__((ext_vector_type(8))) short bf8;
typedef __attribute__((ext_vector_type(8))) unsigned short u16x8;
typedef __attribute__((ext_vector_type(16))) float f32x16;
typedef __attribute__((ext_vector_type(2))) unsigned u32x2;

__device__ __forceinline__ unsigned short f2bf(float x) {
  unsigned u = __builtin_bit_cast(unsigned, x);
  unsigned r = (u + 0x7fffu + ((u >> 16) & 1u)) >> 16;
  return (unsigned short)r;
}
__device__ __forceinline__ float bf2f(unsigned short h) {
  return __builtin_bit_cast(float, ((unsigned)h) << 16);
}
__device__ __forceinline__ float exp2a(float x) {
  float r;
  asm("v_exp_f32 %0, %1" : "=v"(r) : "v"(x));
  return r;  // 2^x
}
// cheap elu: exp(v)-1 = 2^(v*log2e)-1 (abs err ~1e-7, far under bf16 quant)
__device__ __forceinline__ float eluf(float v) {
  return v > 0.f ? v : exp2a(v * LOG2E) - 1.f;
}
__device__ __forceinline__ unsigned cvtpk(float a, float b) {
  unsigned r;
  asm("v_cvt_pk_bf16_f32 %0, %1, %2" : "=v"(r) : "v"(a), "v"(b));
  return r;  // lo = bf16(a), hi = bf16(b)
}

// ---------- prep: weights -> bf16 fragment-order Wfrag; Wzt [n][k]; bn scale/shift ----
// Wfrag element index: ((((t*4+ks)*2+g)*12 + f)*32 + lo)*8 + e
//   f: 0-3 theta, 4-7 g, 8-11 phi (n = (f&3)*32+lo); k = t*64+ks*16+g*8+e
__global__ __launch_bounds__(256) void k_prepw(
    const float* __restrict__ Wth, const float* __restrict__ Wg,
    const float* __restrict__ Wph, const float* __restrict__ Wz,
    const float* __restrict__ g1, const float* __restrict__ b1,
    const float* __restrict__ m1, const float* __restrict__ v1,
    const float* __restrict__ g2, const float* __restrict__ b2,
    const float* __restrict__ m2, const float* __restrict__ v2,
    unsigned short* __restrict__ Wfrag, unsigned short* __restrict__ Wzt,
    float* __restrict__ bn1s, float* __restrict__ bn1h,
    float* __restrict__ bn2s, float* __restrict__ bn2h)
{
  int id = blockIdx.x * 256 + threadIdx.x;
  if (id < 98304) {
    int e = id & 7, lo = (id >> 3) & 31;
    int fg = id >> 8;          // 0..383
    int f = fg % 12;
    int r = fg / 12;           // 0..31
    int g = r & 1, ks = (r >> 1) & 3, t = r >> 3;
    int sel = f >> 2, n2 = f & 3;
    int n = n2 * 32 + lo, k = t * 64 + ks * 16 + g * 8 + e;
    const float* W = (sel == 0) ? Wth : (sel == 1) ? Wg : Wph;
    Wfrag[id] = f2bf(W[(size_t)k * 128 + n]);
  } else {
    int rem = id - 98304;
    int n = rem >> 7, k = rem & 127;
    Wzt[rem] = f2bf(Wz[(size_t)k * 256 + n]);
  }
  if (id < 256) { float s = g1[id] * rsqrtf(v1[id] + BNEPS); bn1s[id] = s; bn1h[id] = b1[id] - m1[id] * s; }
  if (id < 128) { float s = g2[id] * rsqrtf(v2[id] + BNEPS); bn2s[id] = s; bn2h[id] = b2[id] - m2[id] * s; }
}

// ---------- GEMM3 one-pass: A (bn1+elu fused) staged ONCE, 3 outputs ----------
// BM=64, grid 512. B-frags read directly from L2-resident Wfrag (no B LDS).
// Waves 0,1: frags 0-5 (theta 0-3 + g 0-1); waves 2,3: frags 6-11 (g 2-3 + phi 0-3).
__global__ __launch_bounds__(256, 2) void k_gemm3(
    const float* __restrict__ inp, const float* __restrict__ bn1s,
    const float* __restrict__ bn1h, const unsigned short* __restrict__ Wfrag,
    const float* __restrict__ bth, const float* __restrict__ bg,
    const float* __restrict__ bph, unsigned short* __restrict__ Tb,
    unsigned short* __restrict__ Gt2, unsigned short* __restrict__ Pp2)
{
  __shared__ unsigned short As[64][72];
  __shared__ unsigned short Tt[64][136];
  __shared__ float2 bnsh[256];
  const int bm = blockIdx.x * 64;
  const int tid = threadIdx.x;
  const int w = tid >> 6, l = tid & 63;
  const int lo = l & 31, g = l >> 5;
  const int wm = w & 1, nb = (w >> 1) * 6;
  const int srow = tid >> 2, sq = tid & 3;
  if (tid < 256) bnsh[tid] = {bn1s[tid], bn1h[tid]};

  f32x16 acc[6];
#pragma unroll
  for (int i = 0; i < 6; ++i)
#pragma unroll
    for (int j = 0; j < 16; ++j) acc[i][j] = 0.f;

  for (int t = 0; t < 4; ++t) {
    __syncthreads();
    {
      const float* sa = inp + (size_t)(bm + srow) * 256 + t * 64 + sq * 16;
#pragma unroll
      for (int h = 0; h < 2; ++h) {
        float4 v0 = *(const float4*)(sa + h * 8);
        float4 v1 = *(const float4*)(sa + h * 8 + 4);
        int ch = t * 64 + sq * 16 + h * 8;
        float vv[8] = {v0.x, v0.y, v0.z, v0.w, v1.x, v1.y, v1.z, v1.w};
        u16x8 o;
#pragma unroll
        for (int u = 0; u < 8; ++u) {
          float2 sh = bnsh[ch + u];
          o[u] = f2bf(eluf(vv[u] * sh.x + sh.y));
        }
        *(u16x8*)&As[srow][sq * 16 + h * 8] = o;
      }
    }
    __syncthreads();
#pragma unroll
    for (int ks = 0; ks < 4; ++ks) {
      bf8 af = *(const bf8*)&As[wm * 32 + lo][ks * 16 + g * 8];
      const unsigned short* wf =
          Wfrag + (size_t)((((t * 4 + ks) * 2 + g) * 12 + nb) * 32 + lo) * 8;
#pragma unroll
      for (int fi = 0; fi < 6; ++fi) {
        bf8 bF = *(const bf8*)(wf + fi * 256);
        acc[fi] = __builtin_amdgcn_mfma_f32_32x32x16_bf16(af, bF, acc[fi], 0, 0, 0);
      }
    }
  }

  // epilogue: theta -> Tt (LDS transpose); g -> packed u32 scatter; phi -> 2B scatter
#pragma unroll
  for (int fi = 0; fi < 6; ++fi) {
    const int fg = nb + fi;
    if (fg < 4) {               // theta, pre-scaled by log2e for exp2 softmax
      int col = fg * 32 + lo;
      float bv = bth[col];
#pragma unroll
      for (int q = 0; q < 4; ++q)
#pragma unroll
        for (int j = 0; j < 4; ++j)
          Tt[wm * 32 + q * 8 + g * 4 + j][col] = f2bf((acc[fi][q * 4 + j] + bv) * LOG2E);
    } else if (fg < 8) {        // g: width-2 maxpool -> V^T chunk layout
      int col = (fg - 4) * 32 + lo;
      float bv = bg[col];
#pragma unroll
      for (int q = 0; q < 4; ++q) {
        float v0 = acc[fi][q * 4 + 0] + bv, v1 = acc[fi][q * 4 + 1] + bv;
        float v2 = acc[fi][q * 4 + 2] + bv, v3 = acc[fi][q * 4 + 3] + bv;
        float mx01 = fmaxf(v0, v1), mx23 = fmaxf(v2, v3);
        int r = bm + wm * 32 + q * 8 + g * 4;   // even row, j=0
        int pr = r >> 1;
        int b = pr >> 11, local = pr & 2047;
        int kb = local >> 5, sub = (local >> 3) & 3, m = local & 7;  // m even
        unsigned pk = cvtpk(mx01, mx23);
        *(unsigned*)&Gt2[((((size_t)b * 64 + kb) * 4 + sub) * 128 + col) * 8 + m] = pk;
      }
    } else {                    // phi: width-2 maxpool -> chunk layout
      int col = (fg - 8) * 32 + lo;
      float bv = bph[col];
      int csub = col >> 3, e = col & 7;
#pragma unroll
      for (int q = 0; q < 4; ++q) {
        float v0 = acc[fi][q * 4 + 0] + bv, v1 = acc[fi][q * 4 + 1] + bv;
        float v2 = acc[fi][q * 4 + 2] + bv, v3 = acc[fi][q * 4 + 3] + bv;
        float mx01 = fmaxf(v0, v1), mx23 = fmaxf(v2, v3);
        int r = bm + wm * 32 + q * 8 + g * 4;
        int pr = r >> 1;
        int b = pr >> 11, local = pr & 2047;
        int kb = local >> 5, kv = local & 31;   // kv even, kv+1 same kb
        size_t base = (((size_t)(b * 64 + kb) * 16 + csub) * 32 + kv) * 8 + e;
        Pp2[base] = f2bf(mx01);
        Pp2[base + 8] = f2bf(mx23);
      }
    }
  }
  __syncthreads();
  {  // coalesced theta store
    const int rr = tid >> 2, qq = tid & 3;
#pragma unroll
    for (int i = 0; i < 4; ++i) {
      u16x8 vv = *(u16x8*)&Tt[rr][qq * 32 + i * 8];
      *(u16x8*)&Tb[(size_t)(bm + rr) * 128 + qq * 32 + i * 8] = vv;
    }
  }
}

// ---------- MFMA flash attention: KV-split x4, kv-tile 32, reg-staged prefetch ----------
// grid 2048: bid = ((split*64 + qt)*8) + b. Writes bf16 unnormalized O_part + fp32 l_part.
// T14: tile i regs->LDS, barrier, ISSUE tile i+1 loads, compute tile i (latency hidden).
__global__ __launch_bounds__(128, 4) void k_attn(
    const unsigned short* __restrict__ T, const unsigned short* __restrict__ Pp2,
    const unsigned short* __restrict__ Gt2, unsigned short* __restrict__ Opart,
    float* __restrict__ lpart)
{
  __shared__ unsigned short phl[4096];   // [csub=ch>>3][kv 32][8ch]
  __shared__ unsigned short vtl[4096];   // [sub=kv>>3][ch 128][8kv]
  const int bid = blockIdx.x;
  const int b = bid & 7, qt = (bid >> 3) & 63, sp = bid >> 9;
  const int tid = threadIdx.x;
  const int w = tid >> 6, l = tid & 63;
  const int lo = l & 31, g = l >> 5;
  const int qr0 = qt * 64;

  const unsigned short* Tq = T + ((size_t)(b * 4096 + qr0 + w * 32 + lo)) * 128 + g * 8;
  bf8 qf[8];
#pragma unroll
  for (int ks = 0; ks < 8; ++ks) qf[ks] = *(const bf8*)(Tq + ks * 16);

  f32x16 oacc[4];
#pragma unroll
  for (int i = 0; i < 4; ++i)
#pragma unroll
    for (int j = 0; j < 16; ++j) oacc[i][j] = 0.f;
  float lrun = 0.f;

  const unsigned short* Pc = Pp2 + ((size_t)b * 64 + sp * 16) * 4096;
  const unsigned short* Gc = Gt2 + ((size_t)b * 64 + sp * 16) * 4096;
  const int off = w * 2048 + l * 8;   // LDS is a linear copy of the 4096-el chunk

  u16x8 rp[4], rv[4];
#pragma unroll
  for (int j = 0; j < 4; ++j) {       // preload tile 0
    rp[j] = *(const u16x8*)(Pc + off + j * 512);
    rv[j] = *(const u16x8*)(Gc + off + j * 512);
  }

  for (int it = 0; it < 16; ++it) {
    // commit prefetched tile to LDS
#pragma unroll
    for (int j = 0; j < 4; ++j) {
      *(u16x8*)&phl[off + j * 512] = rp[j];
      *(u16x8*)&vtl[off + j * 512] = rv[j];
    }
    __syncthreads();
    if (it < 15) {  // issue next tile's global loads; latency hides under MFMA below
      const unsigned short* ps = Pc + (size_t)(it + 1) * 4096 + off;
      const unsigned short* vs = Gc + (size_t)(it + 1) * 4096 + off;
#pragma unroll
      for (int j = 0; j < 4; ++j) {
        rp[j] = *(const u16x8*)(ps + j * 512);
        rv[j] = *(const u16x8*)(vs + j * 512);
      }
    }

    // S^T = phi_tile(32kv) x Q^T : two independent MFMA chains (even/odd ks)
    __builtin_amdgcn_s_setprio(1);
    f32x16 s0a, s0b;
#pragma unroll
    for (int j = 0; j < 16; ++j) { s0a[j] = 0.f; s0b[j] = 0.f; }
#pragma unroll
    for (int ks = 0; ks < 4; ++ks) {
      bf8 a0 = *(const bf8*)&phl[((2 * ks) * 2 + g) * 256 + lo * 8];
      bf8 a1 = *(const bf8*)&phl[((2 * ks + 1) * 2 + g) * 256 + lo * 8];
      s0a = __builtin_amdgcn_mfma_f32_32x32x16_bf16(a0, qf[2 * ks], s0a, 0, 0, 0);
      s0b = __builtin_amdgcn_mfma_f32_32x32x16_bf16(a1, qf[2 * ks + 1], s0b, 0, 0, 0);
    }
    __builtin_amdgcn_s_setprio(0);

    // no-max softmax: P = 2^(S') (theta pre-scaled by log2e)
    f32x16 s0;
#pragma unroll
    for (int r = 0; r < 16; ++r) { s0[r] = exp2a(s0a[r] + s0b[r]); lrun += s0[r]; }

    // PV: O^T += V^T x P^T ; half-exchange via v_permlane32_swap (VALU, no LDS)
    __builtin_amdgcn_s_setprio(1);
#pragma unroll
    for (int ks2 = 0; ks2 < 2; ++ks2) {
      const int base = 8 * ks2;
      unsigned uA0 = cvtpk(s0[base + 0], s0[base + 1]);
      unsigned uA1 = cvtpk(s0[base + 2], s0[base + 3]);
      unsigned uB0 = cvtpk(s0[base + 4], s0[base + 5]);
      unsigned uB1 = cvtpk(s0[base + 6], s0[base + 7]);
      unsigned sw0 = g ? uA0 : uB0;
      unsigned sw1 = g ? uA1 : uB1;
      unsigned a0 = sw0, b0 = sw0, a1 = sw1, b1 = sw1;
      asm("v_permlane32_swap_b32 %0, %1" : "+v"(a0), "+v"(b0));
      asm("v_permlane32_swap_b32 %0, %1" : "+v"(a1), "+v"(b1));
      unsigned r0 = g ? a0 : b0;
      unsigned r1 = g ? a1 : b1;
      union { bf8 v; unsigned u[4]; } pf;
      if (g == 0) { pf.u[0] = uA0; pf.u[1] = uA1; pf.u[2] = r0; pf.u[3] = r1; }
      else        { pf.u[0] = r0;  pf.u[1] = r1;  pf.u[2] = uB0; pf.u[3] = uB1; }
#pragma unroll
      for (int n2 = 0; n2 < 4; ++n2) {
        bf8 vf = *(const bf8*)&vtl[(ks2 * 2 + g) * 1024 + (n2 * 32 + lo) * 8];
        oacc[n2] = __builtin_amdgcn_mfma_f32_32x32x16_bf16(vf, pf.v, oacc[n2], 0, 0, 0);
      }
    }
    __builtin_amdgcn_s_setprio(0);
    __syncthreads();   // all waves done reading before next commit overwrites
  }

  lrun += __shfl_xor(lrun, 32);
  const int qrow = qr0 + w * 32 + lo;
  unsigned short* Ob = Opart + (size_t)sp * 4194304 + ((size_t)(b * 4096 + qrow)) * 128;
#pragma unroll
  for (int n2 = 0; n2 < 4; ++n2)
#pragma unroll
    for (int q4 = 0; q4 < 4; ++q4) {
      unsigned u0 = cvtpk(oacc[n2][q4 * 4 + 0], oacc[n2][q4 * 4 + 1]);
      unsigned u1 = cvtpk(oacc[n2][q4 * 4 + 2], oacc[n2][q4 * 4 + 3]);
      u32x2 o = {u0, u1};
      *(u32x2*)&Ob[n2 * 32 + q4 * 8 + g * 4] = o;
    }
  if (g == 0) lpart[(size_t)sp * 32768 + b * 4096 + qrow] = lrun;
}

// ---------- final: out = (elu(bn2(sum(Opart)/suml)) @ Wz + bz)*sita + inp ----------
__global__ __launch_bounds__(256) void k_gemm_z(
    const unsigned short* __restrict__ Opart, const float* __restrict__ lp,
    const unsigned short* __restrict__ Wzt,
    const float* __restrict__ bz, const float* __restrict__ bn2s,
    const float* __restrict__ bn2h, const float* __restrict__ inp,
    const float* __restrict__ sita, float* __restrict__ out)
{
  __shared__ unsigned short As[128][72];
  __shared__ unsigned short Bs[128][72];
  const int bm = blockIdx.x * 128, n0 = blockIdx.y * 128;
  const int tid = threadIdx.x;
  const int l = tid & 63, w = tid >> 6, lo = l & 31, g = l >> 5;
  const int row = tid >> 1, hf = tid & 1;
  const size_t grow = (size_t)(bm + row);
  const float inv = 1.f / (lp[grow] + lp[32768 + grow] + lp[65536 + grow] + lp[98304 + grow]);
  f32x16 acc[4];
#pragma unroll
  for (int i = 0; i < 4; ++i)
#pragma unroll
    for (int j = 0; j < 16; ++j) acc[i][j] = 0.f;

  for (int k0 = 0; k0 < 128; k0 += 64) {
    __syncthreads();
    {
      unsigned short tmp[32];
#pragma unroll
      for (int i = 0; i < 4; ++i) {
        size_t off = grow * 128 + k0 + hf * 32 + i * 8;
        u16x8 p0 = *(const u16x8*)&Opart[off];
        u16x8 p1 = *(const u16x8*)&Opart[4194304 + off];
        u16x8 p2 = *(const u16x8*)&Opart[8388608 + off];
        u16x8 p3 = *(const u16x8*)&Opart[12582912 + off];
#pragma unroll
        for (int j = 0; j < 8; ++j) {
          int ch = k0 + hf * 32 + i * 8 + j;
          float y = (bf2f(p0[j]) + bf2f(p1[j]) + bf2f(p2[j]) + bf2f(p3[j])) * inv;
          tmp[i * 8 + j] = f2bf(eluf(y * bn2s[ch] + bn2h[ch]));
        }
      }
#pragma unroll
      for (int i = 0; i < 4; ++i)
        *(u16x8*)&As[row][hf * 32 + i * 8] = *(u16x8*)&tmp[i * 8];
      const unsigned short* sb = Wzt + (size_t)(n0 + row) * 128 + k0 + hf * 32;
#pragma unroll
      for (int i = 0; i < 4; ++i)
        *(u16x8*)&Bs[row][hf * 32 + i * 8] = *(const u16x8*)(sb + i * 8);
    }
    __syncthreads();
#pragma unroll
    for (int ks = 0; ks < 4; ++ks) {
      bf8 af = *(const bf8*)&As[w * 32 + lo][ks * 16 + g * 8];
#pragma unroll
      for (int n2 = 0; n2 < 4; ++n2) {
        bf8 bF = *(const bf8*)&Bs[n2 * 32 + lo][ks * 16 + g * 8];
        acc[n2] = __builtin_amdgcn_mfma_f32_32x32x16_bf16(af, bF, acc[n2], 0, 0, 0);
      }
    }
  }
  float st = sita[0];
#pragma unroll
  for (int n2 = 0; n2 < 4; ++n2) {
    int col = n0 + n2 * 32 + lo;
    float bv = bz[col];
#pragma unroll
    for (int q = 0; q < 4; ++q)
#pragma unroll
      for (int j = 0; j < 4; ++j) {
        size_t r = (size_t)(bm + w * 32 + j + q * 8 + g * 4);
        out[r * 256 + col] = (acc[n2][q * 4 + j] + bv) * st + inp[r * 256 + col];
      }
  }
}

extern "C" void kernel_launch(void* const* d_in, const int* in_sizes, int n_in,
                              void* d_out, int out_size, void* d_ws, size_t ws_size,
                              hipStream_t stream) {
  const float* inp   = (const float*)d_in[0];
  const float* bn1_g = (const float*)d_in[1];
  const float* bn1_b = (const float*)d_in[2];
  const float* bn1_m = (const float*)d_in[3];
  const float* bn1_v = (const float*)d_in[4];
  const float* bn2_g = (const float*)d_in[5];
  const float* bn2_b = (const float*)d_in[6];
  const float* bn2_m = (const float*)d_in[7];
  const float* bn2_v = (const float*)d_in[8];
  const float* W_g   = (const float*)d_in[9];
  const float* b_g   = (const float*)d_in[10];
  const float* W_th  = (const float*)d_in[11];
  const float* b_th  = (const float*)d_in[12];
  const float* W_ph  = (const float*)d_in[13];
  const float* b_ph  = (const float*)d_in[14];
  const float* W_z   = (const float*)d_in[15];
  const float* b_z   = (const float*)d_in[16];
  const float* sita  = (const float*)d_in[17];
  float* out = (float*)d_out;

  float* ws_f = (float*)d_ws;
  float* lp   = ws_f;                 // 4*32768
  float* bn1s = lp + 131072;          // 256
  float* bn1h = bn1s + 256;           // 256
  float* bn2s = bn1h + 256;           // 128
  float* bn2h = bn2s + 128;           // 128
  unsigned short* Opart = (unsigned short*)(bn2h + 128);  // 4*4194304 bf16
  unsigned short* Tb  = Opart + 16777216;                 // 4194304
  unsigned short* Gt2 = Tb + 4194304;                     // 2097152
  unsigned short* Pp2 = Gt2 + 2097152;                    // 2097152
  unsigned short* Wfr = Pp2 + 2097152;                    // 98304
  unsigned short* Wzt = Wfr + 98304;                      // 32768

  k_prepw<<<dim3(512), dim3(256), 0, stream>>>(W_th, W_g, W_ph, W_z,
                                               bn1_g, bn1_b, bn1_m, bn1_v,
                                               bn2_g, bn2_b, bn2_m, bn2_v,
                                               Wfr, Wzt, bn1s, bn1h, bn2s, bn2h);
  k_gemm3<<<dim3(512), dim3(256), 0, stream>>>(inp, bn1s, bn1h, Wfr,
                                               b_th, b_g, b_ph, Tb, Gt2, Pp2);
  k_attn<<<dim3(2048), dim3(128), 0, stream>>>(Tb, Pp2, Gt2, Opart, lp);
  k_gemm_z<<<dim3(256, 2), dim3(256), 0, stream>>>(Opart, lp, Wzt, b_z,
                                                   bn2s, bn2h, inp, sita, out);
}

// Round 10
// 235.614 us; speedup vs baseline: 1.4295x; 1.4295x over previous
//
#include <hip/hip_runtime.h>
#include <math.h>

#define BNEPS 1e-3f
#define LOG2E 1.44269504f

typedef __attribute__((ext_vector_type(8))) short bf8;
typedef __attribute__((ext_vector_type(8))) unsigned short u16x8;
typedef __attribute__((ext_vector_type(16))) float f32x16;
typedef __attribute__((ext_vector_type(2))) unsigned u32x2;

__device__ __forceinline__ unsigned short f2bf(float x) {
  unsigned u = __builtin_bit_cast(unsigned, x);
  unsigned r = (u + 0x7fffu + ((u >> 16) & 1u)) >> 16;
  return (unsigned short)r;
}
__device__ __forceinline__ float bf2f(unsigned short h) {
  return __builtin_bit_cast(float, ((unsigned)h) << 16);
}
__device__ __forceinline__ float exp2a(float x) {
  float r;
  asm("v_exp_f32 %0, %1" : "=v"(r) : "v"(x));
  return r;  // 2^x
}
// cheap elu: exp(v)-1 = 2^(v*log2e)-1 (abs err ~1e-7, far under bf16 quant)
__device__ __forceinline__ float eluf(float v) {
  return v > 0.f ? v : exp2a(v * LOG2E) - 1.f;
}
__device__ __forceinline__ unsigned cvtpk(float a, float b) {
  unsigned r;
  asm("v_cvt_pk_bf16_f32 %0, %1, %2" : "=v"(r) : "v"(a), "v"(b));
  return r;  // lo = bf16(a), hi = bf16(b)
}

#define GLDS(src, dst)                                                          \
  __builtin_amdgcn_global_load_lds(                                             \
      (const __attribute__((address_space(1))) unsigned int*)(src),             \
      (__attribute__((address_space(3))) unsigned int*)(dst), 16, 0, 0)

// ---------- prep: weights -> bf16 fragment-order Wfrag; Wzt [n][k]; bn scale/shift ----
// Wfrag element index: ((((t*4+ks)*2+g)*12 + f)*32 + lo)*8 + e
//   f: 0-3 theta, 4-7 g, 8-11 phi (n = (f&3)*32+lo); k = t*64+ks*16+g*8+e
__global__ __launch_bounds__(256) void k_prepw(
    const float* __restrict__ Wth, const float* __restrict__ Wg,
    const float* __restrict__ Wph, const float* __restrict__ Wz,
    const float* __restrict__ g1, const float* __restrict__ b1,
    const float* __restrict__ m1, const float* __restrict__ v1,
    const float* __restrict__ g2, const float* __restrict__ b2,
    const float* __restrict__ m2, const float* __restrict__ v2,
    unsigned short* __restrict__ Wfrag, unsigned short* __restrict__ Wzt,
    float* __restrict__ bn1s, float* __restrict__ bn1h,
    float* __restrict__ bn2s, float* __restrict__ bn2h)
{
  int id = blockIdx.x * 256 + threadIdx.x;
  if (id < 98304) {
    int e = id & 7, lo = (id >> 3) & 31;
    int fg = id >> 8;          // 0..383
    int f = fg % 12;
    int r = fg / 12;           // 0..31
    int g = r & 1, ks = (r >> 1) & 3, t = r >> 3;
    int sel = f >> 2, n2 = f & 3;
    int n = n2 * 32 + lo, k = t * 64 + ks * 16 + g * 8 + e;
    const float* W = (sel == 0) ? Wth : (sel == 1) ? Wg : Wph;
    Wfrag[id] = f2bf(W[(size_t)k * 128 + n]);
  } else {
    int rem = id - 98304;
    int n = rem >> 7, k = rem & 127;
    Wzt[rem] = f2bf(Wz[(size_t)k * 256 + n]);
  }
  if (id < 256) { float s = g1[id] * rsqrtf(v1[id] + BNEPS); bn1s[id] = s; bn1h[id] = b1[id] - m1[id] * s; }
  if (id < 128) { float s = g2[id] * rsqrtf(v2[id] + BNEPS); bn2s[id] = s; bn2h[id] = b2[id] - m2[id] * s; }
}

// ---------- GEMM3 one-pass: A (bn1+elu fused) staged ONCE, 3 outputs ----------
// BM=64, grid 512. B-frags read directly from L2-resident Wfrag (no B LDS).
// Waves 0,1: frags 0-5 (theta 0-3 + g 0-1); waves 2,3: frags 6-11 (g 2-3 + phi 0-3).
__global__ __launch_bounds__(256, 2) void k_gemm3(
    const float* __restrict__ inp, const float* __restrict__ bn1s,
    const float* __restrict__ bn1h, const unsigned short* __restrict__ Wfrag,
    const float* __restrict__ bth, const float* __restrict__ bg,
    const float* __restrict__ bph, unsigned short* __restrict__ Tb,
    unsigned short* __restrict__ Gt2, unsigned short* __restrict__ Pp2)
{
  __shared__ unsigned short As[64][72];
  __shared__ unsigned short Tt[64][136];
  __shared__ float2 bnsh[256];
  const int bm = blockIdx.x * 64;
  const int tid = threadIdx.x;
  const int w = tid >> 6, l = tid & 63;
  const int lo = l & 31, g = l >> 5;
  const int wm = w & 1, nb = (w >> 1) * 6;
  const int srow = tid >> 2, sq = tid & 3;
  if (tid < 256) bnsh[tid] = {bn1s[tid], bn1h[tid]};

  f32x16 acc[6];
#pragma unroll
  for (int i = 0; i < 6; ++i)
#pragma unroll
    for (int j = 0; j < 16; ++j) acc[i][j] = 0.f;

  for (int t = 0; t < 4; ++t) {
    __syncthreads();
    {
      const float* sa = inp + (size_t)(bm + srow) * 256 + t * 64 + sq * 16;
#pragma unroll
      for (int h = 0; h < 2; ++h) {
        float4 v0 = *(const float4*)(sa + h * 8);
        float4 v1 = *(const float4*)(sa + h * 8 + 4);
        int ch = t * 64 + sq * 16 + h * 8;
        float vv[8] = {v0.x, v0.y, v0.z, v0.w, v1.x, v1.y, v1.z, v1.w};
        u16x8 o;
#pragma unroll
        for (int u = 0; u < 8; ++u) {
          float2 sh = bnsh[ch + u];
          o[u] = f2bf(eluf(vv[u] * sh.x + sh.y));
        }
        *(u16x8*)&As[srow][sq * 16 + h * 8] = o;
      }
    }
    __syncthreads();
#pragma unroll
    for (int ks = 0; ks < 4; ++ks) {
      bf8 af = *(const bf8*)&As[wm * 32 + lo][ks * 16 + g * 8];
      const unsigned short* wf =
          Wfrag + (size_t)((((t * 4 + ks) * 2 + g) * 12 + nb) * 32 + lo) * 8;
#pragma unroll
      for (int fi = 0; fi < 6; ++fi) {
        bf8 bF = *(const bf8*)(wf + fi * 256);
        acc[fi] = __builtin_amdgcn_mfma_f32_32x32x16_bf16(af, bF, acc[fi], 0, 0, 0);
      }
    }
  }

  // epilogue: theta -> Tt (LDS transpose); g -> packed u32 scatter; phi -> 2B scatter
#pragma unroll
  for (int fi = 0; fi < 6; ++fi) {
    const int fg = nb + fi;
    if (fg < 4) {               // theta, pre-scaled by log2e for exp2 softmax
      int col = fg * 32 + lo;
      float bv = bth[col];
#pragma unroll
      for (int q = 0; q < 4; ++q)
#pragma unroll
        for (int j = 0; j < 4; ++j)
          Tt[wm * 32 + q * 8 + g * 4 + j][col] = f2bf((acc[fi][q * 4 + j] + bv) * LOG2E);
    } else if (fg < 8) {        // g: width-2 maxpool -> V^T chunk layout
      int col = (fg - 4) * 32 + lo;
      float bv = bg[col];
#pragma unroll
      for (int q = 0; q < 4; ++q) {
        float v0 = acc[fi][q * 4 + 0] + bv, v1 = acc[fi][q * 4 + 1] + bv;
        float v2 = acc[fi][q * 4 + 2] + bv, v3 = acc[fi][q * 4 + 3] + bv;
        float mx01 = fmaxf(v0, v1), mx23 = fmaxf(v2, v3);
        int r = bm + wm * 32 + q * 8 + g * 4;   // even row, j=0
        int pr = r >> 1;
        int b = pr >> 11, local = pr & 2047;
        int kb = local >> 5, sub = (local >> 3) & 3, m = local & 7;  // m even
        unsigned pk = cvtpk(mx01, mx23);
        *(unsigned*)&Gt2[((((size_t)b * 64 + kb) * 4 + sub) * 128 + col) * 8 + m] = pk;
      }
    } else {                    // phi: width-2 maxpool -> chunk layout
      int col = (fg - 8) * 32 + lo;
      float bv = bph[col];
      int csub = col >> 3, e = col & 7;
#pragma unroll
      for (int q = 0; q < 4; ++q) {
        float v0 = acc[fi][q * 4 + 0] + bv, v1 = acc[fi][q * 4 + 1] + bv;
        float v2 = acc[fi][q * 4 + 2] + bv, v3 = acc[fi][q * 4 + 3] + bv;
        float mx01 = fmaxf(v0, v1), mx23 = fmaxf(v2, v3);
        int r = bm + wm * 32 + q * 8 + g * 4;
        int pr = r >> 1;
        int b = pr >> 11, local = pr & 2047;
        int kb = local >> 5, kv = local & 31;   // kv even, kv+1 same kb
        size_t base = (((size_t)(b * 64 + kb) * 16 + csub) * 32 + kv) * 8 + e;
        Pp2[base] = f2bf(mx01);
        Pp2[base + 8] = f2bf(mx23);
      }
    }
  }
  __syncthreads();
  {  // coalesced theta store
    const int rr = tid >> 2, qq = tid & 3;
#pragma unroll
    for (int i = 0; i < 4; ++i) {
      u16x8 vv = *(u16x8*)&Tt[rr][qq * 32 + i * 8];
      *(u16x8*)&Tb[(size_t)(bm + rr) * 128 + qq * 32 + i * 8] = vv;
    }
  }
}

// ---------- MFMA flash attention: KV-split x4, kv-tile 32, double-buffered GLDS ----------
// grid 2048: bid = ((split*64 + qt)*8) + b. Writes bf16 unnormalized O_part + fp32 l_part.
// 2-phase pipeline: issue GLDS for tile i+1 right after barrier, compute tile i,
// single barrier per iter (its vmcnt(0) drain lands AFTER compute covered the latency).
__global__ __launch_bounds__(128, 4) void k_attn(
    const unsigned short* __restrict__ T, const unsigned short* __restrict__ Pp2,
    const unsigned short* __restrict__ Gt2, unsigned short* __restrict__ Opart,
    float* __restrict__ lpart)
{
  __shared__ unsigned short phl[2][4096];   // [buf][csub=ch>>3][kv 32][8ch]
  __shared__ unsigned short vtl[2][4096];   // [buf][sub=kv>>3][ch 128][8kv]
  const int bid = blockIdx.x;
  const int b = bid & 7, qt = (bid >> 3) & 63, sp = bid >> 9;
  const int tid = threadIdx.x;
  const int w = tid >> 6, l = tid & 63;
  const int lo = l & 31, g = l >> 5;
  const int qr0 = qt * 64;

  const unsigned short* Tq = T + ((size_t)(b * 4096 + qr0 + w * 32 + lo)) * 128 + g * 8;
  bf8 qf[8];
#pragma unroll
  for (int ks = 0; ks < 8; ++ks) qf[ks] = *(const bf8*)(Tq + ks * 16);

  f32x16 oacc[4];
#pragma unroll
  for (int i = 0; i < 4; ++i)
#pragma unroll
    for (int j = 0; j < 16; ++j) oacc[i][j] = 0.f;
  float lrun = 0.f;

  const unsigned short* Pc = Pp2 + ((size_t)b * 64 + sp * 16) * 4096;
  const unsigned short* Gc = Gt2 + ((size_t)b * 64 + sp * 16) * 4096;

#define STAGE_AT(buf, it)                                                       \
  do {                                                                          \
    const unsigned short* ps_ = Pc + (size_t)(it) * 4096 + w * 2048 + l * 8;    \
    const unsigned short* vs_ = Gc + (size_t)(it) * 4096 + w * 2048 + l * 8;    \
    _Pragma("unroll")                                                           \
    for (int j_ = 0; j_ < 4; ++j_) {                                            \
      GLDS(ps_ + j_ * 512, &phl[buf][(w * 4 + j_) * 512]);                      \
      GLDS(vs_ + j_ * 512, &vtl[buf][(w * 4 + j_) * 512]);                      \
    }                                                                           \
  } while (0)

  STAGE_AT(0, 0);
  __syncthreads();   // drain tile-0 DMA

  for (int it = 0; it < 16; ++it) {
    const int cur = it & 1;
    if (it < 15) STAGE_AT(cur ^ 1, it + 1);  // prefetch; drained at END barrier

    // S^T = phi_tile(32kv) x Q^T : lane holds 16 of 32 kv for q-row lo
    __builtin_amdgcn_s_setprio(1);
    f32x16 s0;
#pragma unroll
    for (int j = 0; j < 16; ++j) s0[j] = 0.f;
#pragma unroll
    for (int ks = 0; ks < 8; ++ks) {
      bf8 a0 = *(const bf8*)&phl[cur][(ks * 2 + g) * 256 + lo * 8];
      s0 = __builtin_amdgcn_mfma_f32_32x32x16_bf16(a0, qf[ks], s0, 0, 0, 0);
    }
    __builtin_amdgcn_s_setprio(0);

    // no-max softmax: P = 2^(S') (theta pre-scaled by log2e)
#pragma unroll
    for (int r = 0; r < 16; ++r) { s0[r] = exp2a(s0[r]); lrun += s0[r]; }

    // PV: O^T += V^T x P^T ; half-exchange via v_permlane32_swap (VALU, no LDS)
    __builtin_amdgcn_s_setprio(1);
#pragma unroll
    for (int ks2 = 0; ks2 < 2; ++ks2) {
      const int base = 8 * ks2;
      unsigned uA0 = cvtpk(s0[base + 0], s0[base + 1]);
      unsigned uA1 = cvtpk(s0[base + 2], s0[base + 3]);
      unsigned uB0 = cvtpk(s0[base + 4], s0[base + 5]);
      unsigned uB1 = cvtpk(s0[base + 6], s0[base + 7]);
      unsigned sw0 = g ? uA0 : uB0;
      unsigned sw1 = g ? uA1 : uB1;
      unsigned a0 = sw0, b0 = sw0, a1 = sw1, b1 = sw1;
      asm("v_permlane32_swap_b32 %0, %1" : "+v"(a0), "+v"(b0));
      asm("v_permlane32_swap_b32 %0, %1" : "+v"(a1), "+v"(b1));
      unsigned r0 = g ? a0 : b0;
      unsigned r1 = g ? a1 : b1;
      union { bf8 v; unsigned u[4]; } pf;
      if (g == 0) { pf.u[0] = uA0; pf.u[1] = uA1; pf.u[2] = r0; pf.u[3] = r1; }
      else        { pf.u[0] = r0;  pf.u[1] = r1;  pf.u[2] = uB0; pf.u[3] = uB1; }
#pragma unroll
      for (int n2 = 0; n2 < 4; ++n2) {
        bf8 vf = *(const bf8*)&vtl[cur][(ks2 * 2 + g) * 1024 + (n2 * 32 + lo) * 8];
        oacc[n2] = __builtin_amdgcn_mfma_f32_32x32x16_bf16(vf, pf.v, oacc[n2], 0, 0, 0);
      }
    }
    __builtin_amdgcn_s_setprio(0);
    __syncthreads();   // protects buf reuse; also drains the it+1 prefetch DMA
  }
#undef STAGE_AT

  lrun += __shfl_xor(lrun, 32);
  const int qrow = qr0 + w * 32 + lo;
  unsigned short* Ob = Opart + (size_t)sp * 4194304 + ((size_t)(b * 4096 + qrow)) * 128;
#pragma unroll
  for (int n2 = 0; n2 < 4; ++n2)
#pragma unroll
    for (int q4 = 0; q4 < 4; ++q4) {
      unsigned u0 = cvtpk(oacc[n2][q4 * 4 + 0], oacc[n2][q4 * 4 + 1]);
      unsigned u1 = cvtpk(oacc[n2][q4 * 4 + 2], oacc[n2][q4 * 4 + 3]);
      u32x2 o = {u0, u1};
      *(u32x2*)&Ob[n2 * 32 + q4 * 8 + g * 4] = o;
    }
  if (g == 0) lpart[(size_t)sp * 32768 + b * 4096 + qrow] = lrun;
}

// ---------- final: out = (elu(bn2(sum(Opart)/suml)) @ Wz + bz)*sita + inp ----------
__global__ __launch_bounds__(256) void k_gemm_z(
    const unsigned short* __restrict__ Opart, const float* __restrict__ lp,
    const unsigned short* __restrict__ Wzt,
    const float* __restrict__ bz, const float* __restrict__ bn2s,
    const float* __restrict__ bn2h, const float* __restrict__ inp,
    const float* __restrict__ sita, float* __restrict__ out)
{
  __shared__ unsigned short As[128][72];
  __shared__ unsigned short Bs[128][72];
  const int bm = blockIdx.x * 128, n0 = blockIdx.y * 128;
  const int tid = threadIdx.x;
  const int l = tid & 63, w = tid >> 6, lo = l & 31, g = l >> 5;
  const int row = tid >> 1, hf = tid & 1;
  const size_t grow = (size_t)(bm + row);
  const float inv = 1.f / (lp[grow] + lp[32768 + grow] + lp[65536 + grow] + lp[98304 + grow]);
  f32x16 acc[4];
#pragma unroll
  for (int i = 0; i < 4; ++i)
#pragma unroll
    for (int j = 0; j < 16; ++j) acc[i][j] = 0.f;

  for (int k0 = 0; k0 < 128; k0 += 64) {
    __syncthreads();
    {
      unsigned short tmp[32];
#pragma unroll
      for (int i = 0; i < 4; ++i) {
        size_t off = grow * 128 + k0 + hf * 32 + i * 8;
        u16x8 p0 = *(const u16x8*)&Opart[off];
        u16x8 p1 = *(const u16x8*)&Opart[4194304 + off];
        u16x8 p2 = *(const u16x8*)&Opart[8388608 + off];
        u16x8 p3 = *(const u16x8*)&Opart[12582912 + off];
#pragma unroll
        for (int j = 0; j < 8; ++j) {
          int ch = k0 + hf * 32 + i * 8 + j;
          float y = (bf2f(p0[j]) + bf2f(p1[j]) + bf2f(p2[j]) + bf2f(p3[j])) * inv;
          tmp[i * 8 + j] = f2bf(eluf(y * bn2s[ch] + bn2h[ch]));
        }
      }
#pragma unroll
      for (int i = 0; i < 4; ++i)
        *(u16x8*)&As[row][hf * 32 + i * 8] = *(u16x8*)&tmp[i * 8];
      const unsigned short* sb = Wzt + (size_t)(n0 + row) * 128 + k0 + hf * 32;
#pragma unroll
      for (int i = 0; i < 4; ++i)
        *(u16x8*)&Bs[row][hf * 32 + i * 8] = *(const u16x8*)(sb + i * 8);
    }
    __syncthreads();
#pragma unroll
    for (int ks = 0; ks < 4; ++ks) {
      bf8 af = *(const bf8*)&As[w * 32 + lo][ks * 16 + g * 8];
#pragma unroll
      for (int n2 = 0; n2 < 4; ++n2) {
        bf8 bF = *(const bf8*)&Bs[n2 * 32 + lo][ks * 16 + g * 8];
        acc[n2] = __builtin_amdgcn_mfma_f32_32x32x16_bf16(af, bF, acc[n2], 0, 0, 0);
      }
    }
  }
  float st = sita[0];
#pragma unroll
  for (int n2 = 0; n2 < 4; ++n2) {
    int col = n0 + n2 * 32 + lo;
    float bv = bz[col];
#pragma unroll
    for (int q = 0; q < 4; ++q)
#pragma unroll
      for (int j = 0; j < 4; ++j) {
        size_t r = (size_t)(bm + w * 32 + j + q * 8 + g * 4);
        out[r * 256 + col] = (acc[n2][q * 4 + j] + bv) * st + inp[r * 256 + col];
      }
  }
}

extern "C" void kernel_launch(void* const* d_in, const int* in_sizes, int n_in,
                              void* d_out, int out_size, void* d_ws, size_t ws_size,
                              hipStream_t stream) {
  const float* inp   = (const float*)d_in[0];
  const float* bn1_g = (const float*)d_in[1];
  const float* bn1_b = (const float*)d_in[2];
  const float* bn1_m = (const float*)d_in[3];
  const float* bn1_v = (const float*)d_in[4];
  const float* bn2_g = (const float*)d_in[5];
  const float* bn2_b = (const float*)d_in[6];
  const float* bn2_m = (const float*)d_in[7];
  const float* bn2_v = (const float*)d_in[8];
  const float* W_g   = (const float*)d_in[9];
  const float* b_g   = (const float*)d_in[10];
  const float* W_th  = (const float*)d_in[11];
  const float* b_th  = (const float*)d_in[12];
  const float* W_ph  = (const float*)d_in[13];
  const float* b_ph  = (const float*)d_in[14];
  const float* W_z   = (const float*)d_in[15];
  const float* b_z   = (const float*)d_in[16];
  const float* sita  = (const float*)d_in[17];
  float* out = (float*)d_out;

  float* ws_f = (float*)d_ws;
  float* lp   = ws_f;                 // 4*32768
  float* bn1s = lp + 131072;          // 256
  float* bn1h = bn1s + 256;           // 256
  float* bn2s = bn1h + 256;           // 128
  float* bn2h = bn2s + 128;           // 128
  unsigned short* Opart = (unsigned short*)(bn2h + 128);  // 4*4194304 bf16
  unsigned short* Tb  = Opart + 16777216;                 // 4194304
  unsigned short* Gt2 = Tb + 4194304;                     // 2097152
  unsigned short* Pp2 = Gt2 + 2097152;                    // 2097152
  unsigned short* Wfr = Pp2 + 2097152;                    // 98304
  unsigned short* Wzt = Wfr + 98304;                      // 32768

  k_prepw<<<dim3(512), dim3(256), 0, stream>>>(W_th, W_g, W_ph, W_z,
                                               bn1_g, bn1_b, bn1_m, bn1_v,
                                               bn2_g, bn2_b, bn2_m, bn2_v,
                                               Wfr, Wzt, bn1s, bn1h, bn2s, bn2h);
  k_gemm3<<<dim3(512), dim3(256), 0, stream>>>(inp, bn1s, bn1h, Wfr,
                                               b_th, b_g, b_ph, Tb, Gt2, Pp2);
  k_attn<<<dim3(2048), dim3(128), 0, stream>>>(Tb, Pp2, Gt2, Opart, lp);
  k_gemm_z<<<dim3(256, 2), dim3(256), 0, stream>>>(Opart, lp, Wzt, b_z,
                                                   bn2s, bn2h, inp, sita, out);
}